// Round 1
// baseline (256.731 us; speedup 1.0000x reference)
//
#include <hip/hip_runtime.h>
#include <hip/hip_bf16.h>

// GraphConvolution: out = relu( (W@x + b) @ adj^T + x )
// B=4096, C_in=C_out=256, N=25.
// Strategy: aggregate-first reorder: y[b,c,m] = sum_n x[b,c,n]*adj[m,n],
// then out[b,o,m] = sum_c W[o,c]*y[b,c,m] + b_o*rowsum(adj)[m] + x[b,o,m], relu.
// Big GEMM (13.4 GF) on bf16 MFMA; everything else fp32 VALU. One block per b.

#define BATCH 4096
#define C 256
#define N 25

typedef __bf16 bf16x8 __attribute__((ext_vector_type(8)));
typedef float f32x4 __attribute__((ext_vector_type(4)));

// fp32 W -> bf16 W in workspace (needs 256*256*2 = 128 KiB of d_ws)
__global__ void cvt_w_kernel(const float* __restrict__ W, __bf16* __restrict__ Wb) {
    int i = blockIdx.x * 256 + threadIdx.x;
    Wb[i] = (__bf16)W[i];
}

__global__ __launch_bounds__(256) void gcn_fused_kernel(
    const float* __restrict__ x, const float* __restrict__ adj,
    const float* __restrict__ bias, const __bf16* __restrict__ Wb,
    float* __restrict__ out)
{
    __shared__ float xs[C * N];          // 25600 B: x[b] tile (aggregation + residual)
    __shared__ __bf16 ys[32][C + 8];     // 16896 B: y transposed [m][c], +8 pad breaks b128 bank aliasing
    __shared__ float adjS[32];           // adj row sums (bias folding)
    __shared__ float biasS[C];

    const int tid = threadIdx.x;
    const int b = blockIdx.x;
    const float* xb = x + (size_t)b * (C * N);

    // ---- stage x (float4 coalesced), bias, adj row sums ----
    {
        const float4* xb4 = (const float4*)xb;
        float4* xs4 = (float4*)xs;
        for (int i = tid; i < (C * N) / 4; i += 256) xs4[i] = xb4[i];
    }
    biasS[tid] = bias[tid];
    if (tid < 32) {
        float s = 0.f;
        if (tid < N)
            for (int n = 0; n < N; ++n) s += adj[tid * N + n];
        adjS[tid] = s;
    }
    __syncthreads();

    // ---- aggregation: ys[m][c] = sum_n adj[m][n] * x[c][n], thread t owns c=t ----
    {
        const int c = tid;
        float xr[N];
        #pragma unroll
        for (int n = 0; n < N; ++n) xr[n] = xs[c * N + n];
        #pragma unroll
        for (int m = 0; m < N; ++m) {
            float acc = 0.f;
            #pragma unroll
            for (int n = 0; n < N; ++n) acc = fmaf(adj[m * N + n], xr[n], acc); // adj: uniform addr -> s_load
            ys[m][c] = (__bf16)acc;
        }
        #pragma unroll
        for (int m = N; m < 32; ++m) ys[m][c] = (__bf16)0.f;
    }
    __syncthreads();

    // ---- GEMM on MFMA: wave w owns o in [w*64, w*64+64), all 32 m (25 valid) ----
    const int wv = tid >> 6, lane = tid & 63;
    const int quad = lane >> 4, l15 = lane & 15;
    const int o0 = wv * 64;

    f32x4 acc[4][2];
    #pragma unroll
    for (int ot = 0; ot < 4; ++ot)
        #pragma unroll
        for (int mt = 0; mt < 2; ++mt) acc[ot][mt] = (f32x4)0.f;

    #pragma unroll 2
    for (int kk = 0; kk < 8; ++kk) {
        const int k = kk * 32 + quad * 8;
        // B-fragments: B[k=quad*8+j][n=lane&15] -> ys[n][k], contiguous 16B -> ds_read_b128
        bf16x8 bf[2];
        #pragma unroll
        for (int mt = 0; mt < 2; ++mt)
            bf[mt] = *(const bf16x8*)&ys[mt * 16 + l15][k];
        #pragma unroll
        for (int ot = 0; ot < 4; ++ot) {
            // A-fragment: A[m=lane&15][k=quad*8+j] -> W row, contiguous 16B global (L2-hit)
            bf16x8 af = *(const bf16x8*)&Wb[(size_t)(o0 + ot * 16 + l15) * C + k];
            #pragma unroll
            for (int mt = 0; mt < 2; ++mt)
                acc[ot][mt] = __builtin_amdgcn_mfma_f32_16x16x32_bf16(af, bf[mt], acc[ot][mt], 0, 0, 0);
        }
    }

    // ---- epilogue: C/D layout col=lane&15 (m), row=quad*4+reg (o_local) ----
    float* outb = out + (size_t)b * (C * N);
    #pragma unroll
    for (int ot = 0; ot < 4; ++ot) {
        #pragma unroll
        for (int mt = 0; mt < 2; ++mt) {
            const int m = mt * 16 + l15;
            if (m < N) {
                #pragma unroll
                for (int r = 0; r < 4; ++r) {
                    const int o = o0 + ot * 16 + quad * 4 + r;
                    float v = acc[ot][mt][r] + biasS[o] * adjS[m] + xs[o * N + m];
                    outb[o * N + m] = v > 0.f ? v : 0.f;
                }
            }
        }
    }
}

extern "C" void kernel_launch(void* const* d_in, const int* in_sizes, int n_in,
                              void* d_out, int out_size, void* d_ws, size_t ws_size,
                              hipStream_t stream) {
    (void)in_sizes; (void)n_in; (void)out_size; (void)ws_size;
    const float* x    = (const float*)d_in[0];   // [4096, 256, 25]
    const float* adj  = (const float*)d_in[1];   // [25, 25]
    const float* W    = (const float*)d_in[2];   // [256, 256]
    const float* bias = (const float*)d_in[3];   // [256]
    float* out = (float*)d_out;
    __bf16* Wb = (__bf16*)d_ws;                  // 128 KiB bf16 W

    cvt_w_kernel<<<(C * C) / 256, 256, 0, stream>>>(W, Wb);
    gcn_fused_kernel<<<BATCH, 256, 0, stream>>>(x, adj, bias, Wb, out);
}